// Round 2
// baseline (251.171 us; speedup 1.0000x reference)
//
#include <hip/hip_runtime.h>
#include <stdint.h>

// Gemma4PatchEmbed, fused single-GEMM design (round 2).
//
// wprep:  w_proj fp32 -> bf16 (ws), padding bool -> canonical uint8 mask (ws).
// fused:  per block = 32 patch rows (one ph-row of one image):
//         phase 1: coalesced pixel read -> fp32->bf16 -> LDS A-tile (32 x 768, stride 776)
//         phase 2: barrier-free K-loop; B fragments loaded straight from global bf16
//         (contiguous 16B per lane, L2-resident), A fragments from LDS; 16x16x32 MFMA;
//         fused pos-table gather epilogue.

typedef __attribute__((ext_vector_type(8))) short bfrag_t;       // MFMA A/B operand (8 bf16)
typedef __attribute__((ext_vector_type(4))) float f4_t;           // MFMA C/D
typedef __attribute__((ext_vector_type(8))) unsigned short u16x8;
typedef __attribute__((ext_vector_type(4))) unsigned short u16x4;

#define M_TOT 16384
#define K_TOT 768
#define N_TOT 768
#define V_POS 10240
#define A_STRIDE 776   // shorts; 1552 B/row = 388 dwords; 388%32=4 -> banks rotate +4/row,
                       // 16B-aligned rows -> conflict-free ds_read_b128 fragments

__device__ __forceinline__ unsigned short f2bf(float f) {
    unsigned int u = __float_as_uint(f);
    u += 0x7fffu + ((u >> 16) & 1u);          // RNE fp32->bf16
    return (unsigned short)(u >> 16);
}

// ---------------------------------------------------------------------------
// Kernel 1: tiny prep. blocks [0,288): w_proj -> bf16 (8 elems/thread);
// block 288: padding-bool canonicalization with upload-width detection.
// ---------------------------------------------------------------------------
__global__ __launch_bounds__(256) void wprep_kernel(
    const float* __restrict__ wp, const void* __restrict__ pad_in,
    unsigned short* __restrict__ Wb, unsigned char* __restrict__ mask)
{
    int bid = blockIdx.x, tid = threadIdx.x;
    if (bid < 288) {
        long idx = (long)bid * 256 + tid;     // 0..73727, 8 floats each
        const float4* s = (const float4*)(wp + (idx << 3));
        float4 v0 = s[0];
        float4 v1 = s[1];
        u16x8 o;
        o[0] = f2bf(v0.x); o[1] = f2bf(v0.y); o[2] = f2bf(v0.z); o[3] = f2bf(v0.w);
        o[4] = f2bf(v1.x); o[5] = f2bf(v1.y); o[6] = f2bf(v1.z); o[7] = f2bf(v1.w);
        *(u16x8*)(Wb + (idx << 3)) = o;
    } else {
        // Detect bool upload width. 4096 uints (16 KB) is in-bounds under both
        // interpretations; packed uint8 random bits give some uint > 1.
        __shared__ int u8mode;
        if (tid == 0) u8mode = 0;
        __syncthreads();
        const unsigned int* pi = (const unsigned int*)pad_in;
        int local = 0;
        for (int i = tid; i < 4096; i += 256)
            if (pi[i] > 1u) local = 1;
        if (local) atomicOr(&u8mode, 1);
        __syncthreads();
        if (u8mode) {
            const unsigned char* p8 = (const unsigned char*)pad_in;
            for (int i = tid; i < M_TOT; i += 256) mask[i] = p8[i];
        } else {
            const int* p32 = (const int*)pad_in;
            for (int i = tid; i < M_TOT; i += 256) mask[i] = (unsigned char)(p32[i] != 0);
        }
    }
}

// ---------------------------------------------------------------------------
// Kernel 2: fused patch-extract + GEMM + pos-embed epilogue.
// 512 blocks x 256 threads; block = 32 patch rows (image b = bid>>5, ph = bid&31).
// ---------------------------------------------------------------------------
__global__ __launch_bounds__(256) void fused_kernel(
    const float* __restrict__ px, const unsigned short* __restrict__ Bt,
    const int* __restrict__ pos_ids, const unsigned char* __restrict__ mask,
    const float* __restrict__ pos_table, float* __restrict__ out)
{
    __shared__ unsigned short As[32 * A_STRIDE];   // 49664 B

    const int tid  = threadIdx.x;
    const int wave = tid >> 6;
    const int lane = tid & 63;
    const int bid  = blockIdx.x;
    const int b    = bid >> 5;
    const int ph   = bid & 31;
    const int m0   = bid << 5;

    // ---------------- phase 1: pixels -> bf16 A-tile in LDS ----------------
    // Region: 3 channels x 16 h-rows x 512 w = 6144 float4 (96 KB), coalesced.
    const float* pxb = px + ((size_t)b * 3 * 512 + (size_t)ph * 16) * 512;
#pragma unroll 8
    for (int it = 0; it < 24; ++it) {
        int idx = it * 256 + tid;              // float4 index in region
        int c   = idx >> 11;                   // 2048 float4 per channel
        int rem = idx & 2047;
        int hl  = rem >> 7;                    // h within patch (0..15)
        int w4  = rem & 127;                   // float4 index along W
        float4 v = *(const float4*)(pxb + (size_t)c * 262144 + hl * 512 + (w4 << 2));
        int pw  = w4 >> 2;                     // patch column (row of A)
        int pxo = (w4 & 3) << 2;               // px offset 0/4/8/12
        int k   = c * 256 + hl * 16 + pxo;
        u16x4 o;
        o[0] = f2bf(2.f * v.x - 1.f);
        o[1] = f2bf(2.f * v.y - 1.f);
        o[2] = f2bf(2.f * v.z - 1.f);
        o[3] = f2bf(2.f * v.w - 1.f);
        *(u16x4*)&As[pw * A_STRIDE + k] = o;   // 8B write, 8B-aligned
    }
    __syncthreads();                            // the only barrier in the kernel

    // ---------------- phase 2: barrier-free MFMA K-loop --------------------
    const int fr   = lane & 15;                // A row / B col within 16-tile
    const int quad = lane >> 4;                // k-offset quad*8
    const unsigned short* Aq = As + (size_t)fr * A_STRIDE + (quad << 3);

    for (int nc = 0; nc < 3; ++nc) {
        const int colbase = nc * 256 + (wave << 6);          // wave's 64-col slice
        const unsigned short* Bw = Bt + (size_t)colbase * K_TOT + (quad << 3);

        f4_t acc[2][4] = {};
        bfrag_t a0[2], ac[2], b0[4], b1[4], bc[4];

        // prefetch: B two k-steps deep, A one deep
#pragma unroll
        for (int ni = 0; ni < 4; ++ni)
            b0[ni] = *(const bfrag_t*)(Bw + (size_t)(ni * 16 + fr) * K_TOT);
#pragma unroll
        for (int ni = 0; ni < 4; ++ni)
            b1[ni] = *(const bfrag_t*)(Bw + (size_t)(ni * 16 + fr) * K_TOT + 32);
#pragma unroll
        for (int mi = 0; mi < 2; ++mi)
            a0[mi] = *(const bfrag_t*)(Aq + (size_t)mi * 16 * A_STRIDE);

        for (int kk = 0; kk < 24; kk += 2) {
            // ---- half step A: consume (a0, b0) = k-step kk ----
            int kf = (kk + 2 < 24) ? (kk + 2) * 32 : kk * 32;   // clamped prefetch
#pragma unroll
            for (int mi = 0; mi < 2; ++mi) ac[mi] = a0[mi];
#pragma unroll
            for (int ni = 0; ni < 4; ++ni) bc[ni] = b0[ni];
#pragma unroll
            for (int mi = 0; mi < 2; ++mi)           // A for kk+1
                a0[mi] = *(const bfrag_t*)(Aq + (size_t)mi * 16 * A_STRIDE + (kk + 1) * 32);
#pragma unroll
            for (int ni = 0; ni < 4; ++ni)           // B for kk+2
                b0[ni] = *(const bfrag_t*)(Bw + (size_t)(ni * 16 + fr) * K_TOT + kf);
#pragma unroll
            for (int mi = 0; mi < 2; ++mi)
#pragma unroll
                for (int ni = 0; ni < 4; ++ni)
                    acc[mi][ni] = __builtin_amdgcn_mfma_f32_16x16x32_bf16(
                        ac[mi], bc[ni], acc[mi][ni], 0, 0, 0);

            // ---- half step B: consume (a0, b1) = k-step kk+1 ----
            int kg = (kk + 3 < 24) ? (kk + 3) * 32 : (kk + 1) * 32;
#pragma unroll
            for (int mi = 0; mi < 2; ++mi) ac[mi] = a0[mi];
#pragma unroll
            for (int ni = 0; ni < 4; ++ni) bc[ni] = b1[ni];
            if (kk + 2 < 24) {
#pragma unroll
                for (int mi = 0; mi < 2; ++mi)       // A for kk+2
                    a0[mi] = *(const bfrag_t*)(Aq + (size_t)mi * 16 * A_STRIDE + (kk + 2) * 32);
            }
#pragma unroll
            for (int ni = 0; ni < 4; ++ni)           // B for kk+3
                b1[ni] = *(const bfrag_t*)(Bw + (size_t)(ni * 16 + fr) * K_TOT + kg);
#pragma unroll
            for (int mi = 0; mi < 2; ++mi)
#pragma unroll
                for (int ni = 0; ni < 4; ++ni)
                    acc[mi][ni] = __builtin_amdgcn_mfma_f32_16x16x32_bf16(
                        ac[mi], bc[ni], acc[mi][ni], 0, 0, 0);
        }

        // ---- epilogue: C/D layout col = lane&15, row = quad*4 + reg ----
#pragma unroll
        for (int mi = 0; mi < 2; ++mi) {
#pragma unroll
            for (int reg = 0; reg < 4; ++reg) {
                int gm  = m0 + mi * 16 + (quad << 2) + reg;
                int xid = pos_ids[2 * gm];
                int yid = pos_ids[2 * gm + 1];
                xid = xid < 0 ? 0 : xid;
                yid = yid < 0 ? 0 : yid;
                bool p = mask[gm] != 0;
                const float* t0 = pos_table + (size_t)xid * N_TOT + colbase;
                const float* t1 = pos_table + (size_t)(V_POS + yid) * N_TOT + colbase;
                float* orow = out + (size_t)gm * N_TOT + colbase;
#pragma unroll
                for (int ni = 0; ni < 4; ++ni) {
                    int cc = ni * 16 + fr;
                    float pos = p ? 0.f : (t0[cc] + t1[cc]);
                    orow[cc] = acc[mi][ni][reg] + pos;
                }
            }
        }
    }
}

extern "C" void kernel_launch(void* const* d_in, const int* in_sizes, int n_in,
                              void* d_out, int out_size, void* d_ws, size_t ws_size,
                              hipStream_t stream) {
    const float* px  = (const float*)d_in[0];   // (16,3,512,512)
    const float* wp  = (const float*)d_in[1];   // (768,768)
    const float* pt  = (const float*)d_in[2];   // (2,10240,768)
    const int*   pid = (const int*)d_in[3];     // (16,1024,2)
    const void*  pad = d_in[4];                 // (16,1024) bool

    unsigned short* Wb   = (unsigned short*)d_ws;                        // 1.18 MB bf16
    unsigned char*  mask = (unsigned char*)(Wb + (size_t)N_TOT * K_TOT); // 16 KB

    wprep_kernel<<<289, 256, 0, stream>>>(wp, pad, Wb, mask);
    fused_kernel<<<512, 256, 0, stream>>>(px, Wb, pid, mask, pt, (float*)d_out);
}

// Round 3
// 182.477 us; speedup vs baseline: 1.3765x; 1.3765x over previous
//
#include <hip/hip_runtime.h>
#include <stdint.h>

// Gemma4PatchEmbed round 3: single fused kernel.
// - 128x128 MFMA tile GEMM, BK=64, 768 blocks (3/CU, all co-resident), XCD-swizzled.
// - A staged from pixels through REGISTERS (coalesced float4 -> bf16 -> ds_write),
//   no A materialization, no separate prep pass for A.
// - B staged from a bf16 copy of w_proj (tiny wprep kernel) through registers.
// - Register prefetch of next iter's global data issued before current MFMA phase
//   (overlap the m97-style barrier drain can't express).
// - LDS row stride 80 B (odd 16B-group rotation) -> all LDS access <=2-way (free).
// - Fused pos-table gather epilogue.

typedef __attribute__((ext_vector_type(8))) short bfrag_t;        // MFMA A/B operand
typedef __attribute__((ext_vector_type(4))) float f4_t;            // MFMA C/D
typedef __attribute__((ext_vector_type(8))) unsigned short u16x8;
typedef __attribute__((ext_vector_type(4))) unsigned short u16x4;

#define M_TOT 16384
#define K_TOT 768
#define N_TOT 768
#define V_POS 10240
#define ROWS  40      // LDS row stride in shorts (80 B = 5 x 16B groups, odd -> conflict-free)
#define KSTEP 5120    // shorts per 32-k LDS block (128 rows * 40)

__device__ __forceinline__ unsigned short f2bf(float f) {
    unsigned int u = __float_as_uint(f);
    u += 0x7fffu + ((u >> 16) & 1u);          // RNE fp32 -> bf16
    return (unsigned short)(u >> 16);
}

// ---------------------------------------------------------------------------
// Kernel 1: tiny prep. blocks [0,288): w_proj -> bf16; block 288: padding-bool
// canonicalization with upload-width detection.
// ---------------------------------------------------------------------------
__global__ __launch_bounds__(256) void wprep_kernel(
    const float* __restrict__ wp, const void* __restrict__ pad_in,
    unsigned short* __restrict__ Wb, unsigned char* __restrict__ mask)
{
    int bid = blockIdx.x, tid = threadIdx.x;
    if (bid < 288) {
        long idx = (long)bid * 256 + tid;     // 0..73727, 8 floats each
        const float4* s = (const float4*)(wp + (idx << 3));
        float4 v0 = s[0];
        float4 v1 = s[1];
        u16x8 o;
        o[0] = f2bf(v0.x); o[1] = f2bf(v0.y); o[2] = f2bf(v0.z); o[3] = f2bf(v0.w);
        o[4] = f2bf(v1.x); o[5] = f2bf(v1.y); o[6] = f2bf(v1.z); o[7] = f2bf(v1.w);
        *(u16x8*)(Wb + (idx << 3)) = o;
    } else {
        // Detect bool upload width. 4096 uints (16 KB) in-bounds under both
        // interpretations; packed random uint8 bits give some uint > 1.
        __shared__ int u8mode;
        if (tid == 0) u8mode = 0;
        __syncthreads();
        const unsigned int* pi = (const unsigned int*)pad_in;
        int local = 0;
        for (int i = tid; i < 4096; i += 256)
            if (pi[i] > 1u) local = 1;
        if (local) atomicOr(&u8mode, 1);
        __syncthreads();
        if (u8mode) {
            const unsigned char* p8 = (const unsigned char*)pad_in;
            for (int i = tid; i < M_TOT; i += 256) mask[i] = p8[i];
        } else {
            const int* p32 = (const int*)pad_in;
            for (int i = tid; i < M_TOT; i += 256) mask[i] = (unsigned char)(p32[i] != 0);
        }
    }
}

// ---------------------------------------------------------------------------
// Kernel 2: fused patch-extract + 128x128 GEMM + pos-embed epilogue.
// ---------------------------------------------------------------------------
__global__ __launch_bounds__(256, 3) void fused_kernel(
    const float* __restrict__ px, const unsigned short* __restrict__ Bt,
    const int* __restrict__ pos_ids, const unsigned char* __restrict__ mask,
    const float* __restrict__ pos_table, float* __restrict__ out)
{
    __shared__ unsigned short As[2 * KSTEP];   // 20 KB
    __shared__ unsigned short Bs[2 * KSTEP];   // 20 KB

    const int tid  = threadIdx.x;
    const int wave = tid >> 6;
    const int lane = tid & 63;

    // XCD swizzle: the 6 bn-blocks of each bm group land on one XCD (id%8 heuristic)
    const int id   = blockIdx.x;
    const int xcd  = id & 7;
    const int slot = id >> 3;                 // 0..95
    const int bmg  = slot / 6;
    const int bm   = xcd * 16 + bmg;          // 0..127
    const int bn   = slot - bmg * 6;          // 0..5
    const int m0   = bm << 7;
    const int n0   = bn << 7;
    const int bimg = bm >> 3;                 // image index
    const int ph0  = (bm & 7) << 2;           // first patch-row of this m-tile

    // ---- staging thread mapping ----
    // pixels: thread t covers pixel-row slot r16 = t>>4 (4 ph-subrows x 4 h-lines),
    //         8 float4 along W at f4idx = (t&15) + 16j  (coalesced 256B per 16 lanes)
    const int r16  = tid >> 4;
    const int ph_i = r16 >> 2;
    const int hlr  = r16 & 3;
    const int l16  = tid & 15;
    const int pw_b = l16 >> 2;                // base patch-col
    const int pxo  = (l16 & 3) << 2;          // pixel offset within patch: 0/4/8/12
    const int klA  = hlr * 16 + pxo;          // k_local in [0,64)
    unsigned short* awr = As + (klA >> 5) * KSTEP + ((klA >> 3) & 3) * 8 + (klA & 7);
    const int rowb = ph_i * 32 + pw_b;        // A row, + 4j per f4

    // B: thread t covers col nl = t>>1, k-half kst = t&1 (64 contiguous bytes)
    const int nl  = tid >> 1;
    const int kst = tid & 1;
    const unsigned short* bgbase = Bt + (size_t)(n0 + nl) * K_TOT + kst * 32;
    unsigned short* bwr = Bs + kst * KSTEP + nl * ROWS;

    // ---- compute thread mapping (64x64 per wave, 4x4 sub-tiles) ----
    const int fr      = lane & 15;
    const int quad    = lane >> 4;
    const int row_off = (wave & 1) << 6;
    const int col_off = (wave >> 1) << 6;
    const unsigned short* ards = As + (size_t)(row_off + fr) * ROWS + quad * 8;
    const unsigned short* brds = Bs + (size_t)(col_off + fr) * ROWS + quad * 8;

    float4 P[8];
    u16x8  Q[4];
    // prefetch iteration 0
    {
        const float* prow = px + (((size_t)bimg * 3 + 0) * 512
                                  + (size_t)(ph0 + ph_i) * 16 + hlr) * 512 + (l16 << 2);
#pragma unroll
        for (int j = 0; j < 8; ++j) P[j] = *(const float4*)(prow + (j << 6));
#pragma unroll
        for (int u = 0; u < 4; ++u) Q[u] = *(const u16x8*)(bgbase + (u << 3));
    }

    f4_t acc[4][4] = {};

    for (int kk = 0; kk < 12; ++kk) {
        // ---- write staged tile (A converted to bf16, B copied) ----
#pragma unroll
        for (int j = 0; j < 8; ++j) {
            u16x4 v;
            v[0] = f2bf(2.f * P[j].x - 1.f);
            v[1] = f2bf(2.f * P[j].y - 1.f);
            v[2] = f2bf(2.f * P[j].z - 1.f);
            v[3] = f2bf(2.f * P[j].w - 1.f);
            *(u16x4*)(awr + (rowb + 4 * j) * ROWS) = v;
        }
#pragma unroll
        for (int u = 0; u < 4; ++u)
            *(u16x8*)(bwr + (u << 3)) = Q[u];
        __syncthreads();                       // tile kk ready

        // ---- register prefetch for iter kk+1 (overlaps the MFMA below) ----
        if (kk < 11) {
            const int k2 = kk + 1;
            const int c  = k2 >> 2;
            const int hl = ((k2 & 3) << 2) + hlr;
            const float* prow = px + (((size_t)bimg * 3 + c) * 512
                                      + (size_t)(ph0 + ph_i) * 16 + hl) * 512 + (l16 << 2);
#pragma unroll
            for (int j = 0; j < 8; ++j) P[j] = *(const float4*)(prow + (j << 6));
            const unsigned short* bg = bgbase + k2 * 64;
#pragma unroll
            for (int u = 0; u < 4; ++u) Q[u] = *(const u16x8*)(bg + (u << 3));
        }

        // ---- MFMA on tile kk: 2 k-steps of 32 ----
#pragma unroll
        for (int ks = 0; ks < 2; ++ks) {
            bfrag_t a[4], b[4];
#pragma unroll
            for (int i = 0; i < 4; ++i)
                a[i] = *(const bfrag_t*)(ards + ks * KSTEP + i * 16 * ROWS);
#pragma unroll
            for (int i = 0; i < 4; ++i)
                b[i] = *(const bfrag_t*)(brds + ks * KSTEP + i * 16 * ROWS);
#pragma unroll
            for (int mi = 0; mi < 4; ++mi)
#pragma unroll
                for (int ni = 0; ni < 4; ++ni)
                    acc[mi][ni] = __builtin_amdgcn_mfma_f32_16x16x32_bf16(
                        a[mi], b[ni], acc[mi][ni], 0, 0, 0);
        }
        __syncthreads();                       // done reading before next write
    }

    // ---- epilogue: C/D layout col = lane&15, row = quad*4 + reg ----
#pragma unroll
    for (int mi = 0; mi < 4; ++mi) {
#pragma unroll
        for (int reg = 0; reg < 4; ++reg) {
            int gm  = m0 + row_off + mi * 16 + (quad << 2) + reg;
            int xid = pos_ids[2 * gm];
            int yid = pos_ids[2 * gm + 1];
            xid = xid < 0 ? 0 : xid;
            yid = yid < 0 ? 0 : yid;
            bool p = mask[gm] != 0;
            const float* t0 = pos_table + (size_t)xid * N_TOT + n0 + col_off;
            const float* t1 = pos_table + (size_t)(V_POS + yid) * N_TOT + n0 + col_off;
            float* orow = out + (size_t)gm * N_TOT + n0 + col_off;
#pragma unroll
            for (int ni = 0; ni < 4; ++ni) {
                int cc = ni * 16 + fr;
                float pos = p ? 0.f : (t0[cc] + t1[cc]);
                orow[cc] = acc[mi][ni][reg] + pos;
            }
        }
    }
}

extern "C" void kernel_launch(void* const* d_in, const int* in_sizes, int n_in,
                              void* d_out, int out_size, void* d_ws, size_t ws_size,
                              hipStream_t stream) {
    const float* px  = (const float*)d_in[0];   // (16,3,512,512)
    const float* wp  = (const float*)d_in[1];   // (768,768)
    const float* pt  = (const float*)d_in[2];   // (2,10240,768)
    const int*   pid = (const int*)d_in[3];     // (16,1024,2)
    const void*  pad = d_in[4];                 // (16,1024) bool

    unsigned short* Wb   = (unsigned short*)d_ws;                        // 1.18 MB bf16
    unsigned char*  maskp = (unsigned char*)(Wb + (size_t)N_TOT * K_TOT); // 16 KB

    wprep_kernel<<<289, 256, 0, stream>>>(wp, pad, Wb, maskp);
    fused_kernel<<<768, 256, 0, stream>>>(px, Wb, pid, maskp, pt, (float*)d_out);
}

// Round 4
// 177.299 us; speedup vs baseline: 1.4167x; 1.0292x over previous
//
#include <hip/hip_runtime.h>
#include <stdint.h>

// Gemma4PatchEmbed round 4: ONE kernel. 128x128 tile GEMM (M=16384,N=768,K=768),
// BK=32, double-buffered LDS, one raw s_barrier per K-iter (lgkmcnt(0) only --
// global loads stay in flight across barriers: AITER-style producer/consumer).
// A = pixels (fp32->bf16 with 2x-1, converted in-register), B = w_proj fp32->bf16
// in-register (L2-resident). Fused pos-table gather epilogue + inline bool-width
// detection for padding mask.

typedef __attribute__((ext_vector_type(8))) short bfrag_t;        // MFMA A/B operand
typedef __attribute__((ext_vector_type(4))) float f4_t;            // MFMA C/D
typedef __attribute__((ext_vector_type(4))) unsigned short u16x4;

#define V_POS 10240
#define RS 40          // LDS row stride in shorts (80 B): bank starts 20*r%32 -> balanced
#define ABUF 5120      // shorts per A buffer (128 rows * RS)

__device__ __forceinline__ unsigned short f2bf(float f) {
    unsigned int u = __float_as_uint(f);
    u += 0x7fffu + ((u >> 16) & 1u);          // RNE fp32 -> bf16
    return (unsigned short)(u >> 16);
}

__device__ __forceinline__ void lgkm_barrier() {
    // s_waitcnt lgkmcnt(0) ONLY (vmcnt=63, expcnt=7 untouched): LDS writes visible,
    // global loads stay outstanding across the barrier.
    __builtin_amdgcn_s_waitcnt(0xC07F);
    __builtin_amdgcn_s_barrier();
}

__global__ __launch_bounds__(256, 2) void fused_kernel(
    const float* __restrict__ px, const float* __restrict__ wp,
    const int* __restrict__ pos_ids, const unsigned int* __restrict__ pad_in,
    const float* __restrict__ pos_table, float* __restrict__ out)
{
    __shared__ unsigned short LDS[4 * ABUF];   // As0|As1|Bs0|Bs1 = 40 KB

    const int tid  = threadIdx.x;
    const int wave = tid >> 6;
    const int lane = tid & 63;

    // XCD swizzle: 6 n-blocks of each m-group on one XCD (round-3 verified: FETCH 30 MB)
    const int id   = blockIdx.x;
    const int xcd  = id & 7;
    const int slot = id >> 3;                 // 0..95
    const int bmg  = slot / 6;
    const int bm   = xcd * 16 + bmg;          // 0..127
    const int bn   = slot - bmg * 6;          // 0..5
    const int m0   = bm << 7;
    const int n0   = bn << 7;
    const int bimg = bm >> 3;
    const int ph0  = (bm & 7) << 2;

    // padding-bool upload-width detection (256 B probe, wave-uniform result)
    const bool u8mode = __any(pad_in[lane] > 1u);

    // ---- staging maps (dense per-instruction global reads, balanced LDS writes) ----
    // A: wave region = 2 contiguous image rows (4 KB) for patch-row group (ph0+wave).
    //    chunk j: float4 at region byte j*1024 + lane*16.
    // B: wave region = 32 cols x 128 B of w_proj fp32.
    int aw[4], bw[4], bgb[4];
#pragma unroll
    for (int j = 0; j < 4; ++j) {
        int f4A = j * 64 + lane;              // float4 index in A region
        int kh  = f4A >> 7;                   // which of the 2 rows
        int f4i = f4A & 127;
        int pw  = f4i >> 2;                   // patch column
        int e   = f4i & 3;                    // float4 within 16-float k-chunk
        aw[j] = (wave * 32 + pw) * RS + kh * 16 + e * 4;
        int offb = j * 1024 + lane * 16;      // byte in B region
        int colL = offb >> 7;                 // local col (0..31)
        int win  = offb & 127;                // byte within col's 128-B k-row
        bgb[j] = colL * 3072 + win;           // global byte offset (+ t*128 per tile)
        bw[j]  = (wave * 32 + colL) * RS + (win >> 2);
    }
    const float* abase = px + (((size_t)bimg * 3) * 512 + (size_t)(ph0 + wave) * 16) * 512;
    const char*  bbase = (const char*)(wp + (size_t)(n0 + wave * 32) * 768);
    const int    aglo  = lane * 4;

    float4 FA[2][4], FB[2][4];

    auto load_tile = [&](int t) {
        int s = t & 1;
        const float* ab = abase + (t >> 3) * 262144 + ((t * 2) & 15) * 512;
#pragma unroll
        for (int j = 0; j < 4; ++j)
            FA[s][j] = *(const float4*)(ab + j * 256 + aglo);
        const char* bb = bbase + t * 128;
#pragma unroll
        for (int j = 0; j < 4; ++j)
            FB[s][j] = *(const float4*)(bb + bgb[j]);
    };
    auto store_tile = [&](int t) {
        int s = t & 1;
        unsigned short* A = LDS + s * ABUF;
        unsigned short* B = LDS + 2 * ABUF + s * ABUF;
#pragma unroll
        for (int j = 0; j < 4; ++j) {
            u16x4 v;
            v[0] = f2bf(2.f * FA[s][j].x - 1.f);
            v[1] = f2bf(2.f * FA[s][j].y - 1.f);
            v[2] = f2bf(2.f * FA[s][j].z - 1.f);
            v[3] = f2bf(2.f * FA[s][j].w - 1.f);
            *(u16x4*)(A + aw[j]) = v;
            u16x4 w;
            w[0] = f2bf(FB[s][j].x);
            w[1] = f2bf(FB[s][j].y);
            w[2] = f2bf(FB[s][j].z);
            w[3] = f2bf(FB[s][j].w);
            *(u16x4*)(B + bw[j]) = w;
        }
    };

    // ---- compute mapping: 4 waves = 2x2 of 64x64, each 4x4 of 16x16x32 ----
    const int fr      = lane & 15;
    const int quad    = lane >> 4;
    const int row_off = (wave & 1) << 6;
    const int col_off = (wave >> 1) << 6;

    f4_t acc[4][4] = {};

    // prologue: tiles 0,1 in flight; tile 0 staged
    load_tile(0);
    load_tile(1);
    store_tile(0);
    lgkm_barrier();

#pragma unroll
    for (int kk = 0; kk < 24; ++kk) {
        if (kk < 22) load_tile(kk + 2);       // vmem for k+2: in flight across barriers
        if (kk < 23) store_tile(kk + 1);      // waits vmcnt(N) for k+1's loads only
        const unsigned short* Ab = LDS + (kk & 1) * ABUF + (row_off + fr) * RS + quad * 8;
        const unsigned short* Bb = LDS + 2 * ABUF + (kk & 1) * ABUF + (col_off + fr) * RS + quad * 8;
        bfrag_t a[4], b[4];
#pragma unroll
        for (int i = 0; i < 4; ++i) a[i] = *(const bfrag_t*)(Ab + i * 16 * RS);
#pragma unroll
        for (int i = 0; i < 4; ++i) b[i] = *(const bfrag_t*)(Bb + i * 16 * RS);
#pragma unroll
        for (int mi = 0; mi < 4; ++mi)
#pragma unroll
            for (int ni = 0; ni < 4; ++ni)
                acc[mi][ni] = __builtin_amdgcn_mfma_f32_16x16x32_bf16(
                    a[mi], b[ni], acc[mi][ni], 0, 0, 0);
        if (kk < 23) lgkm_barrier();
    }

    // ---- epilogue: C/D layout col = lane&15, row = quad*4 + reg ----
    const unsigned char* pad8 = (const unsigned char*)pad_in;
    const int colbase = n0 + col_off;
#pragma unroll
    for (int mi = 0; mi < 4; ++mi) {
#pragma unroll
        for (int reg = 0; reg < 4; ++reg) {
            int gm  = m0 + row_off + mi * 16 + (quad << 2) + reg;
            int xid = pos_ids[2 * gm];
            int yid = pos_ids[2 * gm + 1];
            xid = xid < 0 ? 0 : xid;
            yid = yid < 0 ? 0 : yid;
            bool p = u8mode ? (pad8[gm] != 0) : (pad_in[gm] != 0u);
            const float* t0 = pos_table + (size_t)xid * 768 + colbase;
            const float* t1 = pos_table + (size_t)(V_POS + yid) * 768 + colbase;
            float* orow = out + (size_t)gm * 768 + colbase;
#pragma unroll
            for (int ni = 0; ni < 4; ++ni) {
                int cc = ni * 16 + fr;
                float pos = p ? 0.f : (t0[cc] + t1[cc]);
                orow[cc] = acc[mi][ni][reg] + pos;
            }
        }
    }
}

extern "C" void kernel_launch(void* const* d_in, const int* in_sizes, int n_in,
                              void* d_out, int out_size, void* d_ws, size_t ws_size,
                              hipStream_t stream) {
    const float*        px  = (const float*)d_in[0];        // (16,3,512,512)
    const float*        wp  = (const float*)d_in[1];        // (768,768)
    const float*        pt  = (const float*)d_in[2];        // (2,10240,768)
    const int*          pid = (const int*)d_in[3];          // (16,1024,2)
    const unsigned int* pad = (const unsigned int*)d_in[4]; // (16,1024) bool

    fused_kernel<<<768, 256, 0, stream>>>(px, wp, pid, pad, pt, (float*)d_out);
}